// Round 2
// baseline (145.901 us; speedup 1.0000x reference)
//
#include <hip/hip_runtime.h>

#define NPTS 128
#define FAR_DELTA 1e10f

// Kernel 1: one wave (64 lanes) per ray; lane i handles points 2i, 2i+1.
// Computes feat[N,3], raw (un-normalized) depth[N], and block-wise atomicMax
// of depth into ws[0] (float bits as int; values are >= 0).
__global__ __launch_bounds__(256) void vr_main(
    const float* __restrict__ dv,    // [N,128] depth_values
    const float* __restrict__ dens,  // [N,128] density
    const float* __restrict__ feat,  // [N,128,3] feature
    float* __restrict__ out_feat,    // [N,3]
    float* __restrict__ out_depth,   // [N]   (raw, normalized by kernel 2)
    int*   __restrict__ ws_max,      // [1]   float-bits max, pre-zeroed
    int n_rays)
{
    const int lane = threadIdx.x & 63;
    const int wib  = threadIdx.x >> 6;           // wave in block
    const int wpb  = blockDim.x >> 6;            // waves per block
    const int gwave  = blockIdx.x * wpb + wib;
    const int nwaves = gridDim.x * wpb;

    float dmax = 0.0f;                           // wave-uniform running max

    for (int ray = gwave; ray < n_rays; ray += nwaves) {
        const size_t rbase = (size_t)ray * NPTS;
        const float2 d2 = *(const float2*)(dv   + rbase + 2 * lane);
        const float2 s2 = *(const float2*)(dens + rbase + 2 * lane);
        const float2* fp = (const float2*)(feat + rbase * 3);
        const float2 f0 = fp[3 * lane + 0];      // feat[2i][0], feat[2i][1]
        const float2 f1 = fp[3 * lane + 1];      // feat[2i][2], feat[2i+1][0]
        const float2 f2 = fp[3 * lane + 2];      // feat[2i+1][1], feat[2i+1][2]

        // deltas
        const float d_next = __shfl_down(d2.x, 1);            // depth[2i+2]
        const float delta0 = d2.y - d2.x;
        const float delta1 = (lane == 63) ? FAR_DELTA : (d_next - d2.y);

        const float a0 = delta0 * s2.x;
        const float a1 = delta1 * s2.y;

        // Exclusive prefix sum of optical depth across the wave.
        // CRITICAL: lane 63's a1 contains the 1e10 sentinel. It is never
        // needed in any prefix (point 127 is the last), and including it
        // destroys lane 63's excl via catastrophic cancellation
        // (ulp(1e10) ~ 1024). Exclude it from the scan input.
        const float s_scan = (lane == 63) ? a0 : (a0 + a1);
        float pref = s_scan;
        #pragma unroll
        for (int off = 1; off < 64; off <<= 1) {
            const float t = __shfl_up(pref, off);
            if (lane >= off) pref += t;
        }
        const float excl = pref - s_scan;        // sum over points < 2*lane

        // T[2i] = exp(-excl); T[2i+1] = T[2i]*exp(-a0)
        const float T0 = __expf(-excl);
        const float m0 = __expf(-a0);
        const float m1 = __expf(-a1);
        const float w0 = T0 * (1.0f - m0);
        const float w1 = T0 * m0 * (1.0f - m1);

        float c0 = w0 * f0.x + w1 * f1.y;
        float c1 = w0 * f0.y + w1 * f2.x;
        float c2 = w0 * f1.x + w1 * f2.y;

        #pragma unroll
        for (int off = 32; off >= 1; off >>= 1) {
            c0 += __shfl_down(c0, off);
            c1 += __shfl_down(c1, off);
            c2 += __shfl_down(c2, off);
        }

        // depth extraction: first j in [0,50) with density > 0.1
        const bool p0 = (lane < 25) && (s2.x > 0.1f);   // point 2i   (< 50)
        const bool p1 = (lane < 25) && (s2.y > 0.1f);   // point 2i+1 (< 50)
        const unsigned long long b0 = __ballot(p0);
        const unsigned long long b1 = __ballot(p1);
        const int j0 = b0 ? 2 * __builtin_ctzll(b0)     : 1000;
        const int j1 = b1 ? 2 * __builtin_ctzll(b1) + 1 : 1000;
        const int fj = min(j0, j1);
        const float draw = (fj < 50) ? (1.0f - (float)fj * 0.02f) : 0.0f;
        dmax = fmaxf(dmax, draw);

        if (lane == 0) {
            out_feat[(size_t)ray * 3 + 0] = c0;
            out_feat[(size_t)ray * 3 + 1] = c1;
            out_feat[(size_t)ray * 3 + 2] = c2;
            out_depth[ray] = draw;
        }
    }

    // block-level max -> single atomic per block
    __shared__ float smax[8];
    if (lane == 0) smax[wib] = dmax;
    __syncthreads();
    if (threadIdx.x == 0) {
        float m = smax[0];
        for (int i = 1; i < wpb; ++i) m = fmaxf(m, smax[i]);
        atomicMax(ws_max, __float_as_int(m));   // m >= 0: int order == float order
    }
}

// Kernel 2: normalize depth by the global max.
__global__ __launch_bounds__(256) void vr_div(
    float* __restrict__ out_depth, const int* __restrict__ ws_max, int n)
{
    const int i = blockIdx.x * blockDim.x + threadIdx.x;
    const float mx = __int_as_float(*ws_max);
    if (i < n) out_depth[i] = out_depth[i] / mx;
}

extern "C" void kernel_launch(void* const* d_in, const int* in_sizes, int n_in,
                              void* d_out, int out_size, void* d_ws, size_t ws_size,
                              hipStream_t stream) {
    const float* dv   = (const float*)d_in[0];   // [N,128]
    const float* dens = (const float*)d_in[1];   // [N,128,1]
    const float* feat = (const float*)d_in[2];   // [N,128,3]

    const int n_rays = in_sizes[0] / NPTS;

    float* out_feat  = (float*)d_out;            // [N,3]
    float* out_depth = (float*)d_out + (size_t)n_rays * 3;  // [N,1]
    int*   ws_max    = (int*)d_ws;

    hipMemsetAsync(ws_max, 0, sizeof(int), stream);

    const int threads = 256;
    const int blocks  = 2048;   // 8192 waves, grid-stride over rays
    vr_main<<<blocks, threads, 0, stream>>>(dv, dens, feat, out_feat, out_depth,
                                            ws_max, n_rays);

    const int blocks2 = (n_rays + threads - 1) / threads;
    vr_div<<<blocks2, threads, 0, stream>>>(out_depth, ws_max, n_rays);
}

// Round 3
// 137.474 us; speedup vs baseline: 1.0613x; 1.0613x over previous
//
#include <hip/hip_runtime.h>

#define NPTS 128
#define FAR_DELTA 1e10f

// One wave = 2 rays. Lanes [0,32) handle ray 2*pair, lanes [32,64) ray
// 2*pair+1. Each lane owns 4 consecutive points -> all loads are aligned
// float4 (global_load_dwordx4). Scan/reduce confined to each 32-lane half.
__global__ __launch_bounds__(256) void vr_main(
    const float* __restrict__ dv,    // [N,128] depth_values
    const float* __restrict__ dens,  // [N,128] density
    const float* __restrict__ feat,  // [N,128,3] feature
    float* __restrict__ out_feat,    // [N,3]
    float* __restrict__ out_depth,   // [N] raw depth (kernel 2 normalizes)
    int*   __restrict__ ws_max,      // [1] float-bits max, pre-zeroed
    int n_rays)
{
    const int lane = threadIdx.x & 63;
    const int half = lane >> 5;               // which ray of the pair
    const int li   = lane & 31;               // lane within half-wave
    const int wib  = threadIdx.x >> 6;
    const int wpb  = blockDim.x >> 6;
    const int gwave   = blockIdx.x * wpb + wib;
    const int nwaves  = gridDim.x * wpb;
    const int n_pairs = (n_rays + 1) >> 1;

    float dmax = 0.0f;

    for (int pair = gwave; pair < n_pairs; pair += nwaves) {
        const int ray_real = 2 * pair + half;
        const int ray = min(ray_real, n_rays - 1);   // clamp (dup compute ok)
        const size_t pbase = (size_t)ray * NPTS + 4 * li;
        const float4 d4 = *(const float4*)(dv   + pbase);
        const float4 s4 = *(const float4*)(dens + pbase);
        const float* fb = feat + (size_t)ray * (NPTS * 3) + 12 * li;
        const float4 f0 = *(const float4*)(fb + 0);  // p0.xyz, p1.x
        const float4 f1 = *(const float4*)(fb + 4);  // p1.yz, p2.xy
        const float4 f2 = *(const float4*)(fb + 8);  // p2.z, p3.xyz

        // optical depths of the 4 owned segments
        const float dn = __shfl_down(d4.x, 1);       // depth[4(li+1)]
        const float a0 = (d4.y - d4.x) * s4.x;
        const float a1 = (d4.z - d4.y) * s4.y;
        const float a2 = (d4.w - d4.z) * s4.z;
        const float a3 = (li == 31) ? FAR_DELTA * s4.w : (dn - d4.w) * s4.w;

        // Exclusive 32-lane prefix sum. Lane 31's a3 carries the 1e10
        // sentinel: never needed in any prefix; including it destroys excl
        // via catastrophic cancellation (ulp(1e10) ~ 1024). Exclude it.
        const float s_scan = a0 + a1 + a2 + ((li == 31) ? 0.0f : a3);
        float pref = s_scan;
        #pragma unroll
        for (int off = 1; off < 32; off <<= 1) {
            const float t = __shfl_up(pref, off);
            if (li >= off) pref += t;
        }
        const float excl = pref - s_scan;            // sum over points < 4*li

        const float T0 = __expf(-excl);
        const float e0 = __expf(-a0);
        const float e1 = __expf(-a1);
        const float e2 = __expf(-a2);
        const float e3 = __expf(-a3);
        const float w0 = T0 * (1.0f - e0);
        const float T1 = T0 * e0;
        const float w1 = T1 * (1.0f - e1);
        const float T2 = T1 * e1;
        const float w2 = T2 * (1.0f - e2);
        const float T3 = T2 * e2;
        const float w3 = T3 * (1.0f - e3);

        float c0 = w0 * f0.x + w1 * f0.w + w2 * f1.z + w3 * f2.y;
        float c1 = w0 * f0.y + w1 * f1.x + w2 * f1.w + w3 * f2.z;
        float c2 = w0 * f0.z + w1 * f1.y + w2 * f2.x + w3 * f2.w;

        // 32-lane tree reduce (valid chain stays within the half; lanes that
        // read across the half boundary are never consumed afterwards)
        #pragma unroll
        for (int off = 16; off >= 1; off >>= 1) {
            c0 += __shfl_down(c0, off);
            c1 += __shfl_down(c1, off);
            c2 += __shfl_down(c2, off);
        }

        // depth extraction: first j in [0,50) with density > 0.1
        const bool q0 = (li <= 12) && (s4.x > 0.1f);   // j = 4li+0 (<50)
        const bool q1 = (li <= 12) && (s4.y > 0.1f);   // j = 4li+1
        const bool q2 = (li <= 11) && (s4.z > 0.1f);   // j = 4li+2
        const bool q3 = (li <= 11) && (s4.w > 0.1f);   // j = 4li+3
        const unsigned long long b0 = __ballot(q0);
        const unsigned long long b1 = __ballot(q1);
        const unsigned long long b2 = __ballot(q2);
        const unsigned long long b3 = __ballot(q3);
        const int sh = 32 * half;
        const unsigned int m0 = (unsigned int)(b0 >> sh);
        const unsigned int m1 = (unsigned int)(b1 >> sh);
        const unsigned int m2 = (unsigned int)(b2 >> sh);
        const unsigned int m3 = (unsigned int)(b3 >> sh);
        int j = 1000;
        if (m0) j = min(j, 4 * (int)__builtin_ctz(m0) + 0);
        if (m1) j = min(j, 4 * (int)__builtin_ctz(m1) + 1);
        if (m2) j = min(j, 4 * (int)__builtin_ctz(m2) + 2);
        if (m3) j = min(j, 4 * (int)__builtin_ctz(m3) + 3);
        const float draw = (j < 50) ? (1.0f - (float)j * 0.02f) : 0.0f;
        dmax = fmaxf(dmax, draw);

        if (li == 0 && ray_real < n_rays) {
            out_feat[(size_t)ray * 3 + 0] = c0;
            out_feat[(size_t)ray * 3 + 1] = c1;
            out_feat[(size_t)ray * 3 + 2] = c2;
            out_depth[ray] = draw;
        }
    }

    // merge the two halves' maxes, then block max -> one atomic per block
    dmax = fmaxf(dmax, __shfl_xor(dmax, 32));
    __shared__ float smax[8];
    if (lane == 0) smax[wib] = dmax;
    __syncthreads();
    if (threadIdx.x == 0) {
        float m = smax[0];
        for (int i = 1; i < wpb; ++i) m = fmaxf(m, smax[i]);
        atomicMax(ws_max, __float_as_int(m));   // m >= 0: int order == float
    }
}

// Kernel 2: normalize depth by the global max (float4 vectorized).
__global__ __launch_bounds__(256) void vr_div(
    float* __restrict__ out_depth, const int* __restrict__ ws_max, int n)
{
    const int i4 = blockIdx.x * blockDim.x + threadIdx.x;
    const float inv = 1.0f / __int_as_float(*ws_max);
    const int n4 = n >> 2;
    if (i4 < n4) {
        float4 v = ((float4*)out_depth)[i4];
        v.x *= inv; v.y *= inv; v.z *= inv; v.w *= inv;
        ((float4*)out_depth)[i4] = v;
    }
    // tail (n not multiple of 4)
    const int t = n4 * 4 + i4;
    if (i4 < (n & 3) + 0 && t < n && (n & 3)) out_depth[t] *= inv;
}

extern "C" void kernel_launch(void* const* d_in, const int* in_sizes, int n_in,
                              void* d_out, int out_size, void* d_ws, size_t ws_size,
                              hipStream_t stream) {
    const float* dv   = (const float*)d_in[0];   // [N,128]
    const float* dens = (const float*)d_in[1];   // [N,128,1]
    const float* feat = (const float*)d_in[2];   // [N,128,3]

    const int n_rays = in_sizes[0] / NPTS;

    float* out_feat  = (float*)d_out;                       // [N,3]
    float* out_depth = (float*)d_out + (size_t)n_rays * 3;  // [N,1]
    int*   ws_max    = (int*)d_ws;

    hipMemsetAsync(ws_max, 0, sizeof(int), stream);

    const int threads = 256;
    const int blocks  = 2048;   // 8192 waves = 16384 ray-slots, grid-stride
    vr_main<<<blocks, threads, 0, stream>>>(dv, dens, feat, out_feat, out_depth,
                                            ws_max, n_rays);

    const int n4 = (n_rays + 3) / 4;
    const int blocks2 = (n4 + threads - 1) / threads;
    vr_div<<<blocks2, threads, 0, stream>>>(out_depth, ws_max, n_rays);
}

// Round 4
// 123.891 us; speedup vs baseline: 1.1777x; 1.1096x over previous
//
#include <hip/hip_runtime.h>

#define NPTS 128
#define FAR_DELTA 1e10f

typedef float f32x4 __attribute__((ext_vector_type(4)));

// update_dpp with old=0: disabled rows (row_mask) and OOB reads (bound_ctrl)
// yield 0 -- the add identity.
template<int CTRL, int RMASK, bool BC>
__device__ __forceinline__ float dpp0(float x) {
    return __int_as_float(__builtin_amdgcn_update_dpp(
        0, __float_as_int(x), CTRL, RMASK, 0xf, BC));
}

// Inclusive prefix sum within each 32-lane segment, pure VALU (DPP):
// row_shr:1/2/4/8 builds 16-lane row scans; row_bcast:15 adds row0's total
// into row1 (lanes 16-31) and row2's into row3 (lanes 48-63).
// Lane 31 / 63 ends with its segment's total.
__device__ __forceinline__ float scan32(float v) {
    v += dpp0<0x111, 0xf, true>(v);   // row_shr:1
    v += dpp0<0x112, 0xf, true>(v);   // row_shr:2
    v += dpp0<0x114, 0xf, true>(v);   // row_shr:4
    v += dpp0<0x118, 0xf, true>(v);   // row_shr:8
    v += dpp0<0x142, 0xa, false>(v);  // row_bcast:15 -> rows 1,3 only
    return v;
}

// One wave = 2 rays. Lanes [0,32) handle ray 2*pair, lanes [32,64) ray
// 2*pair+1. Each lane owns 4 consecutive points -> all loads are aligned
// float4. Scan/reduce are DPP (VALU), no LDS round-trips.
__global__ __launch_bounds__(256) void vr_main(
    const float* __restrict__ dv,    // [N,128] depth_values
    const float* __restrict__ dens,  // [N,128] density
    const float* __restrict__ feat,  // [N,128,3] feature
    float* __restrict__ out_feat,    // [N,3]
    float* __restrict__ out_depth,   // [N] raw depth (kernel 2 normalizes)
    int*   __restrict__ ws_max,      // [1] float-bits max, pre-zeroed
    int n_rays)
{
    const int lane = threadIdx.x & 63;
    const int half = lane >> 5;               // which ray of the pair
    const int li   = lane & 31;               // lane within half-wave
    const int wib  = threadIdx.x >> 6;
    const int wpb  = blockDim.x >> 6;
    const int gwave   = blockIdx.x * wpb + wib;
    const int nwaves  = gridDim.x * wpb;
    const int n_pairs = (n_rays + 1) >> 1;

    float dmax = 0.0f;

    for (int pair = gwave; pair < n_pairs; pair += nwaves) {
        const int ray_real = 2 * pair + half;
        const int ray = min(ray_real, n_rays - 1);   // clamp (dup compute ok)
        const size_t pbase = (size_t)ray * NPTS + 4 * li;
        // dv/dens lines are touched exactly once -> nontemporal.
        const f32x4 d4 = __builtin_nontemporal_load((const f32x4*)(dv   + pbase));
        const f32x4 s4 = __builtin_nontemporal_load((const f32x4*)(dens + pbase));
        // feat lines are touched by 3 strided instructions -> keep cached.
        const float* fb = feat + (size_t)ray * (NPTS * 3) + 12 * li;
        const f32x4 f0 = *(const f32x4*)(fb + 0);  // p0.xyz, p1.x
        const f32x4 f1 = *(const f32x4*)(fb + 4);  // p1.yz, p2.xy
        const f32x4 f2 = *(const f32x4*)(fb + 8);  // p2.z, p3.xyz

        // optical depths of the 4 owned segments
        const float dn = __shfl_down(d4.x, 1);       // depth[4(li+1)]
        const float a0 = (d4.y - d4.x) * s4.x;
        const float a1 = (d4.z - d4.y) * s4.y;
        const float a2 = (d4.w - d4.z) * s4.z;
        const float a3 = (li == 31) ? FAR_DELTA * s4.w : (dn - d4.w) * s4.w;

        // Exclusive prefix of optical depth. Lane 31's a3 carries the 1e10
        // sentinel: never needed in any prefix; including it destroys excl
        // via catastrophic cancellation (ulp(1e10) ~ 1024). Exclude it.
        const float s_scan = a0 + a1 + a2 + ((li == 31) ? 0.0f : a3);
        const float incl = scan32(s_scan);
        const float excl = incl - s_scan;            // sum over points < 4*li

        const float T0 = __expf(-excl);
        const float e0 = __expf(-a0);
        const float e1 = __expf(-a1);
        const float e2 = __expf(-a2);
        const float e3 = __expf(-a3);
        const float w0 = T0 * (1.0f - e0);
        const float T1 = T0 * e0;
        const float w1 = T1 * (1.0f - e1);
        const float T2 = T1 * e1;
        const float w2 = T2 * (1.0f - e2);
        const float T3 = T2 * e2;
        const float w3 = T3 * (1.0f - e3);

        float c0 = w0 * f0.x + w1 * f0.w + w2 * f1.z + w3 * f2.y;
        float c1 = w0 * f0.y + w1 * f1.x + w2 * f1.w + w3 * f2.z;
        float c2 = w0 * f0.z + w1 * f1.y + w2 * f2.x + w3 * f2.w;

        // Segment sums via the same DPP scan: lane 31/63 holds the total.
        c0 = scan32(c0);
        c1 = scan32(c1);
        c2 = scan32(c2);

        // depth extraction: first j in [0,50) with density > 0.1
        const bool q0 = (li <= 12) && (s4.x > 0.1f);   // j = 4li+0 (<50)
        const bool q1 = (li <= 12) && (s4.y > 0.1f);   // j = 4li+1
        const bool q2 = (li <= 11) && (s4.z > 0.1f);   // j = 4li+2
        const bool q3 = (li <= 11) && (s4.w > 0.1f);   // j = 4li+3
        const unsigned long long b0 = __ballot(q0);
        const unsigned long long b1 = __ballot(q1);
        const unsigned long long b2 = __ballot(q2);
        const unsigned long long b3 = __ballot(q3);
        const int sh = 32 * half;
        const unsigned int m0 = (unsigned int)(b0 >> sh);
        const unsigned int m1 = (unsigned int)(b1 >> sh);
        const unsigned int m2 = (unsigned int)(b2 >> sh);
        const unsigned int m3 = (unsigned int)(b3 >> sh);
        int j = 1000;
        if (m0) j = min(j, 4 * (int)__builtin_ctz(m0) + 0);
        if (m1) j = min(j, 4 * (int)__builtin_ctz(m1) + 1);
        if (m2) j = min(j, 4 * (int)__builtin_ctz(m2) + 2);
        if (m3) j = min(j, 4 * (int)__builtin_ctz(m3) + 3);
        const float draw = (j < 50) ? (1.0f - (float)j * 0.02f) : 0.0f;
        dmax = fmaxf(dmax, draw);

        if (li == 31 && ray_real < n_rays) {          // lane holding the sums
            out_feat[(size_t)ray * 3 + 0] = c0;
            out_feat[(size_t)ray * 3 + 1] = c1;
            out_feat[(size_t)ray * 3 + 2] = c2;
            out_depth[ray] = draw;
        }
    }

    // merge the two halves' maxes, then block max -> one atomic per block
    dmax = fmaxf(dmax, __shfl_xor(dmax, 32));
    __shared__ float smax[8];
    if (lane == 0) smax[wib] = dmax;
    __syncthreads();
    if (threadIdx.x == 0) {
        float m = smax[0];
        for (int i = 1; i < wpb; ++i) m = fmaxf(m, smax[i]);
        atomicMax(ws_max, __float_as_int(m));   // m >= 0: int order == float
    }
}

// Kernel 2: normalize depth by the global max (float4 vectorized).
__global__ __launch_bounds__(256) void vr_div(
    float* __restrict__ out_depth, const int* __restrict__ ws_max, int n)
{
    const int i4 = blockIdx.x * blockDim.x + threadIdx.x;
    const float inv = 1.0f / __int_as_float(*ws_max);
    const int n4 = n >> 2;
    if (i4 < n4) {
        f32x4 v = ((f32x4*)out_depth)[i4];
        v.x *= inv; v.y *= inv; v.z *= inv; v.w *= inv;
        ((f32x4*)out_depth)[i4] = v;
    }
    const int rem = n & 3;
    if (rem && i4 < rem) {
        const int t = n4 * 4 + i4;
        out_depth[t] *= inv;
    }
}

extern "C" void kernel_launch(void* const* d_in, const int* in_sizes, int n_in,
                              void* d_out, int out_size, void* d_ws, size_t ws_size,
                              hipStream_t stream) {
    const float* dv   = (const float*)d_in[0];   // [N,128]
    const float* dens = (const float*)d_in[1];   // [N,128,1]
    const float* feat = (const float*)d_in[2];   // [N,128,3]

    const int n_rays = in_sizes[0] / NPTS;

    float* out_feat  = (float*)d_out;                       // [N,3]
    float* out_depth = (float*)d_out + (size_t)n_rays * 3;  // [N,1]
    int*   ws_max    = (int*)d_ws;

    hipMemsetAsync(ws_max, 0, sizeof(int), stream);

    const int threads = 256;
    const int blocks  = 2048;   // 8192 waves = 16384 ray-slots, grid-stride
    vr_main<<<blocks, threads, 0, stream>>>(dv, dens, feat, out_feat, out_depth,
                                            ws_max, n_rays);

    const int n4 = (n_rays + 3) / 4;
    const int blocks2 = (n4 + threads - 1) / threads;
    vr_div<<<blocks2, threads, 0, stream>>>(out_depth, ws_max, n_rays);
}